// Round 1
// baseline (436.776 us; speedup 1.0000x reference)
//
#include <hip/hip_runtime.h>
#include <cstdint>

#define M_ 8192
#define N_ 4096
#define K_ 4096
#define E_ 8

typedef unsigned short u16;
typedef __bf16 bf16x8 __attribute__((ext_vector_type(8)));
typedef float  f32x4  __attribute__((ext_vector_type(4)));
typedef u16    u16x8  __attribute__((ext_vector_type(8)));

__device__ __forceinline__ u16 f2bf(float f) {
  union { float f; uint32_t u; } v; v.f = f;
  uint32_t u = v.u;
  return (u16)((u + 0x7fffu + ((u >> 16) & 1u)) >> 16);  // RNE
}

__device__ __forceinline__ void async16(const u16* g, u16* l) {
  __builtin_amdgcn_global_load_lds(
      (const __attribute__((address_space(1))) void*)g,
      (__attribute__((address_space(3))) void*)l, 16, 0, 0);
}

// ---------------- prologue: x (f32) -> bf16 ----------------
__global__ void cvt_x_kernel(const float* __restrict__ x, u16* __restrict__ xb) {
  const long total8 = (long)M_ * K_ / 8;
  long t = (long)blockIdx.x * blockDim.x + threadIdx.x;
  const long stride = (long)gridDim.x * blockDim.x;
  for (; t < total8; t += stride) {
    long e = t * 8;
    float4 a = *(const float4*)(x + e);
    float4 b = *(const float4*)(x + e + 4);
    u16x8 r;
    r[0] = f2bf(a.x); r[1] = f2bf(a.y); r[2] = f2bf(a.z); r[3] = f2bf(a.w);
    r[4] = f2bf(b.x); r[5] = f2bf(b.y); r[6] = f2bf(b.z); r[7] = f2bf(b.w);
    *(u16x8*)(xb + e) = r;
  }
}

// ---------------- prologue: W dequant -> bf16 ----------------
__global__ void build_w_kernel(const int* __restrict__ wi, const float* __restrict__ zp,
                               const float* __restrict__ dout, const float* __restrict__ din,
                               const int* __restrict__ eidx, u16* __restrict__ wb) {
  const int e = *eidx;
  const long total8 = (long)N_ * K_ / 8;
  long t = (long)blockIdx.x * blockDim.x + threadIdx.x;
  const long stride = (long)gridDim.x * blockDim.x;
  const float* dine = din + (long)e * K_;
  const float* doute = dout + (long)e * N_;
  for (; t < total8; t += stride) {
    long eo = t * 8;
    int o = (int)(eo >> 12);          // / K_
    int c = (int)(eo & (K_ - 1));
    float z  = zp[o];
    float so = doute[o];
    int4 w0 = *(const int4*)(wi + eo);
    int4 w1 = *(const int4*)(wi + eo + 4);
    float4 d0 = *(const float4*)(dine + c);
    float4 d1 = *(const float4*)(dine + c + 4);
    u16x8 r;
    r[0] = f2bf(((float)w0.x - z) * so * d0.x);
    r[1] = f2bf(((float)w0.y - z) * so * d0.y);
    r[2] = f2bf(((float)w0.z - z) * so * d0.z);
    r[3] = f2bf(((float)w0.w - z) * so * d0.w);
    r[4] = f2bf(((float)w1.x - z) * so * d1.x);
    r[5] = f2bf(((float)w1.y - z) * so * d1.y);
    r[6] = f2bf(((float)w1.z - z) * so * d1.z);
    r[7] = f2bf(((float)w1.w - z) * so * d1.w);
    *(u16x8*)(wb + eo) = r;
  }
}

// ---------------- main: bf16 NT GEMM (m97 structure) ----------------
// A: (M_, K_) bf16 K-major; B: (N_, K_) bf16 K-major; C = A @ B^T + bias
__global__ __launch_bounds__(256) void gemm_kernel(const u16* __restrict__ A,
                                                   const u16* __restrict__ B,
                                                   const float* __restrict__ bias,
                                                   float* __restrict__ C) {
  __shared__ u16 As[128 * 64];
  __shared__ u16 Bs[128 * 64];
  const int tid  = threadIdx.x;
  const int lane = tid & 63;
  const int wave = tid >> 6;
  const int wr = wave >> 1, wc = wave & 1;   // 2x2 waves, 64x64 each
  const int fr = lane & 15, fq = lane >> 4;

  // XCD-aware swizzle (2048 % 8 == 0 -> simple form is bijective)
  const int nwg = gridDim.x;
  const int wg  = blockIdx.x;
  const int cpx = nwg >> 3;
  const int swz = (wg & 7) * cpx + (wg >> 3);
  const int bm = swz >> 5;          // N_/128 = 32 tiles in N
  const int bn = swz & 31;
  const long brow = (long)bm * 128;
  const long bcol = (long)bn * 128;

  f32x4 acc[4][4] = {};

  for (int k0 = 0; k0 < K_; k0 += 64) {
#pragma unroll
    for (int r = 0; r < 4; ++r) {
      int chunk = r * 256 + tid;          // 1024 chunks x 16B = 16KB tile
      int row = chunk >> 3;
      int col = (chunk & 7) << 3;
      async16(&A[(brow + row) * K_ + k0 + col], &As[chunk * 8]);
      async16(&B[(bcol + row) * K_ + k0 + col], &Bs[chunk * 8]);
    }
    __syncthreads();

    bf16x8 af[2][4], bfr[2][4];
#pragma unroll
    for (int kk = 0; kk < 2; ++kk) {
#pragma unroll
      for (int m = 0; m < 4; ++m)
        af[kk][m] = *(const bf16x8*)&As[(wr * 64 + m * 16 + fr) * 64 + kk * 32 + fq * 8];
#pragma unroll
      for (int n = 0; n < 4; ++n)
        bfr[kk][n] = *(const bf16x8*)&Bs[(wc * 64 + n * 16 + fr) * 64 + kk * 32 + fq * 8];
    }
#pragma unroll
    for (int kk = 0; kk < 2; ++kk)
#pragma unroll
      for (int m = 0; m < 4; ++m)
#pragma unroll
        for (int n = 0; n < 4; ++n)
          acc[m][n] = __builtin_amdgcn_mfma_f32_16x16x32_bf16(af[kk][m], bfr[kk][n],
                                                              acc[m][n], 0, 0, 0);
    __syncthreads();
  }

  // epilogue: C/D layout col=lane&15, row=(lane>>4)*4+reg  [m89-verified]
  const int  ocol0 = (int)bcol + wc * 64;
  const long orow0 = brow + wr * 64;
  float bv[4];
#pragma unroll
  for (int n = 0; n < 4; ++n) bv[n] = bias[ocol0 + n * 16 + fr];
#pragma unroll
  for (int m = 0; m < 4; ++m) {
    long rb = orow0 + m * 16 + fq * 4;
#pragma unroll
    for (int n = 0; n < 4; ++n) {
      int col = ocol0 + n * 16 + fr;
#pragma unroll
      for (int j = 0; j < 4; ++j)
        C[(rb + j) * N_ + col] = acc[m][n][j] + bv[n];
    }
  }
}

// ---------------- fallback (only if ws too small) ----------------
__global__ void naive_kernel(const float* __restrict__ x, const int* __restrict__ wi,
                             const float* __restrict__ zp, const float* __restrict__ dout,
                             const float* __restrict__ din, const float* __restrict__ bias,
                             const int* __restrict__ eidx, float* __restrict__ y) {
  long t = (long)blockIdx.x * blockDim.x + threadIdx.x;
  if (t >= (long)M_ * N_) return;
  int  o = (int)(t & (N_ - 1));
  long r = t >> 12;
  int  e = *eidx;
  float z  = zp[o];
  float so = dout[(long)e * N_ + o];
  const float* xr = x + r * K_;
  const int*   wrow = wi + (long)o * K_;
  const float* dr = din + (long)e * K_;
  float s = 0.f;
  for (int k = 0; k < K_; ++k)
    s += xr[k] * (((float)wrow[k] - z) * dr[k]);
  y[t] = s * so + bias[o];
}

extern "C" void kernel_launch(void* const* d_in, const int* in_sizes, int n_in,
                              void* d_out, int out_size, void* d_ws, size_t ws_size,
                              hipStream_t stream) {
  const float* x    = (const float*)d_in[0];
  const int*   wi   = (const int*)d_in[1];
  const float* zp   = (const float*)d_in[2];
  const float* dout = (const float*)d_in[3];
  const float* din  = (const float*)d_in[4];
  const float* bias = (const float*)d_in[5];
  const int*   eidx = (const int*)d_in[6];
  float* y = (float*)d_out;

  const size_t need = (size_t)M_ * K_ * 2 + (size_t)N_ * K_ * 2;
  if (ws_size >= need) {
    u16* xb = (u16*)d_ws;
    u16* wb = xb + (size_t)M_ * K_;
    cvt_x_kernel<<<dim3(2048), dim3(256), 0, stream>>>(x, xb);
    build_w_kernel<<<dim3(2048), dim3(256), 0, stream>>>(wi, zp, dout, din, eidx, wb);
    gemm_kernel<<<dim3((M_ / 128) * (N_ / 128)), dim3(256), 0, stream>>>(xb, wb, bias, y);
  } else {
    long total = (long)M_ * N_;
    naive_kernel<<<dim3((unsigned)((total + 255) / 256)), dim3(256), 0, stream>>>(
        x, wi, zp, dout, din, bias, eidx, y);
  }
}

// Round 2
// 289.441 us; speedup vs baseline: 1.5090x; 1.5090x over previous
//
#include <hip/hip_runtime.h>
#include <cstdint>

#define M_ 8192
#define N_ 4096
#define K_ 4096

typedef unsigned short u16;
typedef __bf16 bf16x8 __attribute__((ext_vector_type(8)));
typedef float  f32x4  __attribute__((ext_vector_type(4)));
typedef u16    u16x8  __attribute__((ext_vector_type(8)));

__device__ __forceinline__ u16 f2bf(float f) {
  union { float f; uint32_t u; } v; v.f = f;
  uint32_t u = v.u;
  return (u16)((u + 0x7fffu + ((u >> 16) & 1u)) >> 16);  // RNE
}

__device__ __forceinline__ void async16(const u16* g, u16* l) {
  __builtin_amdgcn_global_load_lds(
      (const __attribute__((address_space(1))) void*)g,
      (__attribute__((address_space(3))) void*)l, 16, 0, 0);
}

// ---------------- prologue: x (f32) -> bf16 ----------------
__global__ void cvt_x_kernel(const float* __restrict__ x, u16* __restrict__ xb) {
  const long total8 = (long)M_ * K_ / 8;
  long t = (long)blockIdx.x * blockDim.x + threadIdx.x;
  const long stride = (long)gridDim.x * blockDim.x;
  for (; t < total8; t += stride) {
    long e = t * 8;
    float4 a = *(const float4*)(x + e);
    float4 b = *(const float4*)(x + e + 4);
    u16x8 r;
    r[0] = f2bf(a.x); r[1] = f2bf(a.y); r[2] = f2bf(a.z); r[3] = f2bf(a.w);
    r[4] = f2bf(b.x); r[5] = f2bf(b.y); r[6] = f2bf(b.z); r[7] = f2bf(b.w);
    *(u16x8*)(xb + e) = r;
  }
}

// ---------------- prologue: W dequant -> bf16 ----------------
__global__ void build_w_kernel(const int* __restrict__ wi, const float* __restrict__ zp,
                               const float* __restrict__ dout, const float* __restrict__ din,
                               const int* __restrict__ eidx, u16* __restrict__ wb) {
  const int e = *eidx;
  const long total8 = (long)N_ * K_ / 8;
  long t = (long)blockIdx.x * blockDim.x + threadIdx.x;
  const long stride = (long)gridDim.x * blockDim.x;
  const float* dine = din + (long)e * K_;
  const float* doute = dout + (long)e * N_;
  for (; t < total8; t += stride) {
    long eo = t * 8;
    int o = (int)(eo >> 12);          // / K_
    int c = (int)(eo & (K_ - 1));
    float z  = zp[o];
    float so = doute[o];
    int4 w0 = *(const int4*)(wi + eo);
    int4 w1 = *(const int4*)(wi + eo + 4);
    float4 d0 = *(const float4*)(dine + c);
    float4 d1 = *(const float4*)(dine + c + 4);
    u16x8 r;
    r[0] = f2bf(((float)w0.x - z) * so * d0.x);
    r[1] = f2bf(((float)w0.y - z) * so * d0.y);
    r[2] = f2bf(((float)w0.z - z) * so * d0.z);
    r[3] = f2bf(((float)w0.w - z) * so * d0.w);
    r[4] = f2bf(((float)w1.x - z) * so * d1.x);
    r[5] = f2bf(((float)w1.y - z) * so * d1.y);
    r[6] = f2bf(((float)w1.z - z) * so * d1.z);
    r[7] = f2bf(((float)w1.w - z) * so * d1.w);
    *(u16x8*)(wb + eo) = r;
  }
}

// ---------------- main GEMM: 256x256 tile, BK=32, 4-deep ring, counted vmcnt ----
// A: (M_, K_) bf16 K-major; B: (N_, K_) bf16 K-major; C = A @ B^T + bias
// LDS ring: 4 buffers x (A 16KB + B 16KB) = 128 KB (dynamic).
// XOR swizzle: 16B-slot ^= (row>>1)&3, applied on pre-swizzled global source
// (linear gload_lds dest) and on ds_read address (rule #21, both-sides).
__global__ __launch_bounds__(512, 2) void gemm_kernel(const u16* __restrict__ A,
                                                      const u16* __restrict__ B,
                                                      const float* __restrict__ bias,
                                                      float* __restrict__ C) {
  extern __shared__ u16 lds[];
  const int tid  = threadIdx.x;
  const int lane = tid & 63;
  const int wave = tid >> 6;          // 0..7
  const int wm = wave >> 2;           // 0..1   M half (128 rows)
  const int wn = wave & 3;            // 0..3   N quarter (64 cols)
  const int fr = lane & 15, fq = lane >> 4;

  // XCD-aware swizzle: 512 blocks, 512 % 8 == 0 -> bijective simple form
  const int nwg = gridDim.x;
  const int wg  = blockIdx.x;
  const int swz = (wg & 7) * (nwg >> 3) + (wg >> 3);
  const int bm = swz >> 4;            // 32 M-tiles
  const int bn = swz & 15;            // 16 N-tiles
  const long brow = (long)bm * 256;
  const long bcol = (long)bn * 256;

  // staging descriptors: 2 rounds for A, 2 for B (4 x 16B loads/thread/K-tile)
  const u16* gA[2]; const u16* gB[2];
  int Lo[2];
#pragma unroll
  for (int r = 0; r < 2; ++r) {
    int L = tid * 16 + r * 8192;      // byte offset within a 16KB half (A or B)
    int row  = L >> 6;                // 64 B per row (32 bf16)
    int col8 = ((L >> 4) & 3) ^ ((row >> 1) & 3);   // inverse-swizzled source
    gA[r] = A + (brow + row) * (long)K_ + col8 * 8;
    gB[r] = B + (bcol + row) * (long)K_ + col8 * 8;
    Lo[r] = L;
  }

  // fragment LDS element offsets (within a buffer's A / B region), swizzled read
  int offA[8], offB[4];
#pragma unroll
  for (int m = 0; m < 8; ++m) {
    int row = wm * 128 + m * 16 + fr;
    offA[m] = row * 32 + ((fq ^ ((row >> 1) & 3)) << 3);
  }
#pragma unroll
  for (int n = 0; n < 4; ++n) {
    int row = wn * 64 + n * 16 + fr;
    offB[n] = row * 32 + ((fq ^ ((row >> 1) & 3)) << 3);
  }

  f32x4 acc[8][4] = {};
  const int nk = K_ / 32;             // 128 K-tiles

  auto STAGE = [&](int tt) {
    const int bb = (tt & 3) * 32768;  // ring-buffer byte base
    const int k0 = tt * 32;           // K element offset
#pragma unroll
    for (int r = 0; r < 2; ++r) {
      async16(gA[r] + k0, (u16*)((char*)lds + bb + Lo[r]));
      async16(gB[r] + k0, (u16*)((char*)lds + bb + 16384 + Lo[r]));
    }
  };

  // prologue: stage tiles 0,1,2 (12 loads/thread in flight)
  STAGE(0); STAGE(1); STAGE(2);

#define GEMM_ITER(T, VM, DOSTAGE)                                               \
  {                                                                             \
    asm volatile("s_waitcnt vmcnt(" #VM ")" ::: "memory");                      \
    __builtin_amdgcn_s_barrier();                                               \
    if (DOSTAGE) STAGE((T) + 3);                                                \
    const u16* abuf = (const u16*)((const char*)lds + ((T) & 3) * 32768);       \
    const u16* bbuf = abuf + 8192;                                              \
    bf16x8 af[8], bfv[4];                                                       \
    _Pragma("unroll")                                                           \
    for (int n = 0; n < 4; ++n) bfv[n] = *(const bf16x8*)(bbuf + offB[n]);      \
    _Pragma("unroll")                                                           \
    for (int m = 0; m < 8; ++m) af[m] = *(const bf16x8*)(abuf + offA[m]);       \
    __builtin_amdgcn_s_setprio(1);                                              \
    _Pragma("unroll")                                                           \
    for (int m = 0; m < 8; ++m)                                                 \
      _Pragma("unroll")                                                         \
      for (int n = 0; n < 4; ++n)                                               \
        acc[m][n] = __builtin_amdgcn_mfma_f32_16x16x32_bf16(af[m], bfv[n],      \
                                                            acc[m][n], 0, 0, 0);\
    __builtin_amdgcn_s_setprio(0);                                              \
  }

  for (int t = 0; t < nk - 3; ++t) { GEMM_ITER(t, 8, 1) }
  { int t = nk - 3; GEMM_ITER(t, 8, 0) }
  { int t = nk - 2; GEMM_ITER(t, 4, 0) }
  { int t = nk - 1; GEMM_ITER(t, 0, 0) }
#undef GEMM_ITER

  // epilogue: C/D layout col=lane&15, row=(lane>>4)*4+reg  [m89-verified]
  const int  ocol0 = (int)bcol + wn * 64;
  const long orow0 = brow + wm * 128;
  float bv[4];
#pragma unroll
  for (int n = 0; n < 4; ++n) bv[n] = bias[ocol0 + n * 16 + fr];
#pragma unroll
  for (int m = 0; m < 8; ++m) {
    long rb = orow0 + m * 16 + fq * 4;
#pragma unroll
    for (int n = 0; n < 4; ++n) {
      int col = ocol0 + n * 16 + fr;
#pragma unroll
      for (int j = 0; j < 4; ++j)
        C[(rb + j) * N_ + col] = acc[m][n][j] + bv[n];
    }
  }
}

// ---------------- fallback (only if ws too small) ----------------
__global__ void naive_kernel(const float* __restrict__ x, const int* __restrict__ wi,
                             const float* __restrict__ zp, const float* __restrict__ dout,
                             const float* __restrict__ din, const float* __restrict__ bias,
                             const int* __restrict__ eidx, float* __restrict__ y) {
  long t = (long)blockIdx.x * blockDim.x + threadIdx.x;
  if (t >= (long)M_ * N_) return;
  int  o = (int)(t & (N_ - 1));
  long r = t >> 12;
  int  e = *eidx;
  float z  = zp[o];
  float so = dout[(long)e * N_ + o];
  const float* xr = x + r * K_;
  const int*   wrow = wi + (long)o * K_;
  const float* dr = din + (long)e * K_;
  float s = 0.f;
  for (int k = 0; k < K_; ++k)
    s += xr[k] * (((float)wrow[k] - z) * dr[k]);
  y[t] = s * so + bias[o];
}

extern "C" void kernel_launch(void* const* d_in, const int* in_sizes, int n_in,
                              void* d_out, int out_size, void* d_ws, size_t ws_size,
                              hipStream_t stream) {
  const float* x    = (const float*)d_in[0];
  const int*   wi   = (const int*)d_in[1];
  const float* zp   = (const float*)d_in[2];
  const float* dout = (const float*)d_in[3];
  const float* din  = (const float*)d_in[4];
  const float* bias = (const float*)d_in[5];
  const int*   eidx = (const int*)d_in[6];
  float* y = (float*)d_out;

  const size_t need = (size_t)M_ * K_ * 2 + (size_t)N_ * K_ * 2;
  if (ws_size >= need) {
    u16* xb = (u16*)d_ws;
    u16* wb = xb + (size_t)M_ * K_;
    cvt_x_kernel<<<dim3(2048), dim3(256), 0, stream>>>(x, xb);
    build_w_kernel<<<dim3(2048), dim3(256), 0, stream>>>(wi, zp, dout, din, eidx, wb);
    (void)hipFuncSetAttribute((const void*)gemm_kernel,
                              hipFuncAttributeMaxDynamicSharedMemorySize, 131072);
    gemm_kernel<<<dim3((M_ / 256) * (N_ / 256)), dim3(512), 131072, stream>>>(xb, wb, bias, y);
  } else {
    long total = (long)M_ * N_;
    naive_kernel<<<dim3((unsigned)((total + 255) / 256)), dim3(256), 0, stream>>>(
        x, wi, zp, dout, din, bias, eidx, y);
  }
}

// Round 3
// 280.086 us; speedup vs baseline: 1.5594x; 1.0334x over previous
//
#include <hip/hip_runtime.h>
#include <cstdint>

#define M_ 8192
#define N_ 4096
#define K_ 4096

typedef unsigned short u16;
typedef __bf16 bf16x8 __attribute__((ext_vector_type(8)));
typedef float  f32x4  __attribute__((ext_vector_type(4)));
typedef u16    u16x8  __attribute__((ext_vector_type(8)));

__device__ __forceinline__ u16 f2bf(float f) {
  union { float f; uint32_t u; } v; v.f = f;
  uint32_t u = v.u;
  return (u16)((u + 0x7fffu + ((u >> 16) & 1u)) >> 16);  // RNE
}

__device__ __forceinline__ void async16(const u16* g, void* l) {
  __builtin_amdgcn_global_load_lds(
      (const __attribute__((address_space(1))) void*)g,
      (__attribute__((address_space(3))) void*)l, 16, 0, 0);
}

// ---------------- prologue: x (f32) -> bf16 ----------------
__global__ void cvt_x_kernel(const float* __restrict__ x, u16* __restrict__ xb) {
  const long total8 = (long)M_ * K_ / 8;
  long t = (long)blockIdx.x * blockDim.x + threadIdx.x;
  const long stride = (long)gridDim.x * blockDim.x;
  for (; t < total8; t += stride) {
    long e = t * 8;
    float4 a = *(const float4*)(x + e);
    float4 b = *(const float4*)(x + e + 4);
    u16x8 r;
    r[0] = f2bf(a.x); r[1] = f2bf(a.y); r[2] = f2bf(a.z); r[3] = f2bf(a.w);
    r[4] = f2bf(b.x); r[5] = f2bf(b.y); r[6] = f2bf(b.z); r[7] = f2bf(b.w);
    *(u16x8*)(xb + e) = r;
  }
}

// ---------------- prologue: W dequant -> bf16 ----------------
__global__ void build_w_kernel(const int* __restrict__ wi, const float* __restrict__ zp,
                               const float* __restrict__ dout, const float* __restrict__ din,
                               const int* __restrict__ eidx, u16* __restrict__ wb) {
  const int e = *eidx;
  const long total8 = (long)N_ * K_ / 8;
  long t = (long)blockIdx.x * blockDim.x + threadIdx.x;
  const long stride = (long)gridDim.x * blockDim.x;
  const float* dine = din + (long)e * K_;
  const float* doute = dout + (long)e * N_;
  for (; t < total8; t += stride) {
    long eo = t * 8;
    int o = (int)(eo >> 12);
    int c = (int)(eo & (K_ - 1));
    float z  = zp[o];
    float so = doute[o];
    int4 w0 = *(const int4*)(wi + eo);
    int4 w1 = *(const int4*)(wi + eo + 4);
    float4 d0 = *(const float4*)(dine + c);
    float4 d1 = *(const float4*)(dine + c + 4);
    u16x8 r;
    r[0] = f2bf(((float)w0.x - z) * so * d0.x);
    r[1] = f2bf(((float)w0.y - z) * so * d0.y);
    r[2] = f2bf(((float)w0.z - z) * so * d0.z);
    r[3] = f2bf(((float)w0.w - z) * so * d0.w);
    r[4] = f2bf(((float)w1.x - z) * so * d1.x);
    r[5] = f2bf(((float)w1.y - z) * so * d1.y);
    r[6] = f2bf(((float)w1.z - z) * so * d1.z);
    r[7] = f2bf(((float)w1.w - z) * so * d1.w);
    *(u16x8*)(wb + eo) = r;
  }
}

// ------------- main GEMM: 256x256, BK=64, dbuf=2, 4-phase/K-tile (m201 port) ----
// A: (M_,K_) bf16 K-major; B: (N_,K_) bf16 K-major; C = A@B^T + bias.
// LDS per buf: A 32KB [256 rows x 128B] + B 32KB; halves of 16KB each.
// Swizzle: 16B-slot ^= (row&7); staged via inverse-swizzled global source
// (linear gload_lds dest) and swizzled ds_read (both-sides, rule #21).
// Stage schedule (derived overwrite-safe): P0:(t+1)Ahi P1:(t+2)Blo
// P2:(t+2)Bhi P3:(t+2)Alo; vmcnt(6) at P3 => 3 half-tiles in flight.
#define SBAR()  asm volatile("s_barrier" ::: "memory")
#define LGKM0() asm volatile("s_waitcnt lgkmcnt(0)" ::: "memory")

__global__ __launch_bounds__(512, 2) void gemm_kernel(const u16* __restrict__ A,
                                                      const u16* __restrict__ B,
                                                      const float* __restrict__ bias,
                                                      float* __restrict__ C) {
  extern __shared__ char ldsb[];
  const int tid  = threadIdx.x;
  const int lane = tid & 63;
  const int wave = tid >> 6;
  const int wm = wave >> 2;            // 0..1 -> 128-row half
  const int wn = wave & 3;             // 0..3 -> 64-col quarter
  const int fr = lane & 15, fq = lane >> 4;

  // XCD-aware swizzle (512 % 8 == 0 -> bijective)
  const int nwg = gridDim.x;
  const int wg  = blockIdx.x;
  const int swz = (wg & 7) * (nwg >> 3) + (wg >> 3);
  const int bm = swz >> 4;
  const int bn = swz & 15;
  const long brow = (long)bm * 256;
  const long bcol = (long)bn * 256;

  // staging: 2 x 16B loads per thread per 16KB half; linear LDS dest,
  // inverse-swizzled global source column
  const int L0 = tid * 16, L1 = tid * 16 + 8192;
  const int srow = tid >> 3;                       // row of load r=0 (r=1: +64)
  const int sslot = (tid & 7) ^ ((tid >> 3) & 7);  // inverse-swizzled 16B slot
  const u16* sA0 = A + (brow + srow) * (long)K_ + sslot * 8;
  const u16* sA1 = A + (brow + srow + 64) * (long)K_ + sslot * 8;
  const u16* sB0 = B + (bcol + srow) * (long)K_ + sslot * 8;
  const u16* sB1 = B + (bcol + srow + 64) * (long)K_ + sslot * 8;

  auto STAGE = [&](int tile, int which) {   // which: 0=Alo 1=Ahi 2=Blo 3=Bhi
    const long off = (long)(which & 1) * 128 * K_ + (long)tile * 64;
    char* dst = ldsb + ((tile & 1) * 65536 + which * 16384);
    if (which >= 2) {
      async16(sB0 + off, dst + L0);
      async16(sB1 + off, dst + L1);
    } else {
      async16(sA0 + off, dst + L0);
      async16(sA1 + off, dst + L1);
    }
  };

  // ds_read offsets (elements): row*64 + ((kk*4+fq)^(fr&7))*8 ; row&7 == fr&7
  const int sl0 = ((fq ^ (fr & 7)) << 3);            // kk=0 slot bytes/2: elements*... (elements)
  const int sl1 = (((4 + fq) ^ (fr & 7)) << 3);
  const int rowA = (wm * 128 + fr) * 64;
  const int rowB = (wn * 64 + fr) * 64;

  f32x4 acc[8][4] = {};
  bf16x8 bA[8], bB0[4], bB1[4];        // bA: [m(0..3)][kk]; B halves: [n][kk]

  const int nk = K_ / 64;              // 64 K-tiles

  // prologue staging: tile0 all, tile1 Blo,Bhi,Alo  (14 loads)
  STAGE(0, 2); STAGE(0, 3); STAGE(0, 0); STAGE(0, 1);
  STAGE(1, 2); STAGE(1, 3); STAGE(1, 0);
  asm volatile("s_waitcnt vmcnt(6)" ::: "memory");
  SBAR();

  for (int t = 0; t < nk; ++t) {
    const u16* areg = (const u16*)(ldsb + (t & 1) * 65536);
    const u16* breg = areg + 16384;
    const bool s0 = (t + 1 < nk);
    const bool s1 = (t + 2 < nk);

    // ---- P0: read B0(n0,1) + A(m0..3); MFMA acc[0..3][0..1]
#pragma unroll
    for (int n = 0; n < 2; ++n) {
      bB0[n * 2]     = *(const bf16x8*)(breg + rowB + n * 1024 + sl0);
      bB0[n * 2 + 1] = *(const bf16x8*)(breg + rowB + n * 1024 + sl1);
    }
#pragma unroll
    for (int m = 0; m < 4; ++m) {
      bA[m * 2]     = *(const bf16x8*)(areg + rowA + m * 1024 + sl0);
      bA[m * 2 + 1] = *(const bf16x8*)(areg + rowA + m * 1024 + sl1);
    }
    if (s0) STAGE(t + 1, 1);
    SBAR(); LGKM0();
    __builtin_amdgcn_s_setprio(1);
#pragma unroll
    for (int kk = 0; kk < 2; ++kk)
#pragma unroll
      for (int m = 0; m < 4; ++m)
#pragma unroll
        for (int n = 0; n < 2; ++n)
          acc[m][n] = __builtin_amdgcn_mfma_f32_16x16x32_bf16(bA[m * 2 + kk], bB0[n * 2 + kk], acc[m][n], 0, 0, 0);
    __builtin_amdgcn_s_setprio(0);
    SBAR();

    // ---- P1: read B1(n2,3); MFMA acc[0..3][2..3]
#pragma unroll
    for (int n = 0; n < 2; ++n) {
      bB1[n * 2]     = *(const bf16x8*)(breg + rowB + (n + 2) * 1024 + sl0);
      bB1[n * 2 + 1] = *(const bf16x8*)(breg + rowB + (n + 2) * 1024 + sl1);
    }
    if (s1) STAGE(t + 2, 2);
    SBAR(); LGKM0();
    __builtin_amdgcn_s_setprio(1);
#pragma unroll
    for (int kk = 0; kk < 2; ++kk)
#pragma unroll
      for (int m = 0; m < 4; ++m)
#pragma unroll
        for (int n = 0; n < 2; ++n)
          acc[m][n + 2] = __builtin_amdgcn_mfma_f32_16x16x32_bf16(bA[m * 2 + kk], bB1[n * 2 + kk], acc[m][n + 2], 0, 0, 0);
    __builtin_amdgcn_s_setprio(0);
    SBAR();

    // ---- P2: read A(m4..7); MFMA acc[4..7][2..3]
#pragma unroll
    for (int m = 0; m < 4; ++m) {
      bA[m * 2]     = *(const bf16x8*)(areg + rowA + (m + 4) * 1024 + sl0);
      bA[m * 2 + 1] = *(const bf16x8*)(areg + rowA + (m + 4) * 1024 + sl1);
    }
    if (s1) STAGE(t + 2, 3);
    SBAR(); LGKM0();
    __builtin_amdgcn_s_setprio(1);
#pragma unroll
    for (int kk = 0; kk < 2; ++kk)
#pragma unroll
      for (int m = 0; m < 4; ++m)
#pragma unroll
        for (int n = 0; n < 2; ++n)
          acc[m + 4][n + 2] = __builtin_amdgcn_mfma_f32_16x16x32_bf16(bA[m * 2 + kk], bB1[n * 2 + kk], acc[m + 4][n + 2], 0, 0, 0);
    __builtin_amdgcn_s_setprio(0);
    SBAR();

    // ---- P3: no reads; MFMA acc[4..7][0..1]; stage (t+2)Alo; tile-boundary vmcnt
    if (s1) STAGE(t + 2, 0);
    if (t < nk - 2) { asm volatile("s_waitcnt vmcnt(6)" ::: "memory"); }
    else            { asm volatile("s_waitcnt vmcnt(0)" ::: "memory"); }
    SBAR();
    __builtin_amdgcn_s_setprio(1);
#pragma unroll
    for (int kk = 0; kk < 2; ++kk)
#pragma unroll
      for (int m = 0; m < 4; ++m)
#pragma unroll
        for (int n = 0; n < 2; ++n)
          acc[m + 4][n] = __builtin_amdgcn_mfma_f32_16x16x32_bf16(bA[m * 2 + kk], bB0[n * 2 + kk], acc[m + 4][n], 0, 0, 0);
    __builtin_amdgcn_s_setprio(0);
    SBAR();
  }

  // epilogue: C/D layout col=lane&15, row=(lane>>4)*4+reg  [m89-verified]
  const int  ocol0 = (int)bcol + wn * 64;
  const long orow0 = brow + wm * 128;
  float bv[4];
#pragma unroll
  for (int n = 0; n < 4; ++n) bv[n] = bias[ocol0 + n * 16 + fr];
#pragma unroll
  for (int m = 0; m < 8; ++m) {
    long rb = orow0 + m * 16 + fq * 4;
#pragma unroll
    for (int n = 0; n < 4; ++n) {
      int col = ocol0 + n * 16 + fr;
#pragma unroll
      for (int j = 0; j < 4; ++j)
        C[(rb + j) * N_ + col] = acc[m][n][j] + bv[n];
    }
  }
}

// ---------------- fallback (only if ws too small) ----------------
__global__ void naive_kernel(const float* __restrict__ x, const int* __restrict__ wi,
                             const float* __restrict__ zp, const float* __restrict__ dout,
                             const float* __restrict__ din, const float* __restrict__ bias,
                             const int* __restrict__ eidx, float* __restrict__ y) {
  long t = (long)blockIdx.x * blockDim.x + threadIdx.x;
  if (t >= (long)M_ * N_) return;
  int  o = (int)(t & (N_ - 1));
  long r = t >> 12;
  int  e = *eidx;
  float z  = zp[o];
  float so = dout[(long)e * N_ + o];
  const float* xr = x + r * K_;
  const int*   wrow = wi + (long)o * K_;
  const float* dr = din + (long)e * K_;
  float s = 0.f;
  for (int k = 0; k < K_; ++k)
    s += xr[k] * (((float)wrow[k] - z) * dr[k]);
  y[t] = s * so + bias[o];
}

extern "C" void kernel_launch(void* const* d_in, const int* in_sizes, int n_in,
                              void* d_out, int out_size, void* d_ws, size_t ws_size,
                              hipStream_t stream) {
  const float* x    = (const float*)d_in[0];
  const int*   wi   = (const int*)d_in[1];
  const float* zp   = (const float*)d_in[2];
  const float* dout = (const float*)d_in[3];
  const float* din  = (const float*)d_in[4];
  const float* bias = (const float*)d_in[5];
  const int*   eidx = (const int*)d_in[6];
  float* y = (float*)d_out;

  const size_t need = (size_t)M_ * K_ * 2 + (size_t)N_ * K_ * 2;
  if (ws_size >= need) {
    u16* xb = (u16*)d_ws;
    u16* wb = xb + (size_t)M_ * K_;
    cvt_x_kernel<<<dim3(2048), dim3(256), 0, stream>>>(x, xb);
    build_w_kernel<<<dim3(2048), dim3(256), 0, stream>>>(wi, zp, dout, din, eidx, wb);
    (void)hipFuncSetAttribute((const void*)gemm_kernel,
                              hipFuncAttributeMaxDynamicSharedMemorySize, 131072);
    gemm_kernel<<<dim3((M_ / 256) * (N_ / 256)), dim3(512), 131072, stream>>>(xb, wb, bias, y);
  } else {
    long total = (long)M_ * N_;
    naive_kernel<<<dim3((unsigned)((total + 255) / 256)), dim3(256), 0, stream>>>(
        x, wi, zp, dout, din, bias, eidx, y);
  }
}